// Round 15
// baseline (275.534 us; speedup 1.0000x reference)
//
#include <hip/hip_runtime.h>
#include <hip/hip_bf16.h>

#define NFEAT 500
#define DIM   64
#define NCLS  40
#define EPS_FA 0.3f
#define NPB   32      // nodes per agg block (4 waves x 8 groups)
#define LDSE  1024    // staged edges per block (mean 512)
#define NCHUNK 256    // edge chunks for bucket partition
#define BSH   9       // bucket = 512 nodes

typedef __attribute__((ext_vector_type(8))) __bf16 bf16x8;
typedef __attribute__((ext_vector_type(4))) float  f32x4;

__device__ __forceinline__ float bflo(unsigned int u) {
  return __uint_as_float(u << 16);
}
__device__ __forceinline__ float bfhi(unsigned int u) {
  return __uint_as_float(u & 0xffff0000u);
}
__device__ __forceinline__ float fast_tanh(float x) {
  return 1.f - 2.f / (__expf(2.f * x) + 1.f);
}
__device__ __forceinline__ float sigm(float w) {
  return (__builtin_fabsf(w) > 0.f) ? (1.f / (1.f + __expf(-w))) : 0.f;
}
__device__ __forceinline__ unsigned int packbf(float a, float b) {
  __bf16 x = (__bf16)a, y = (__bf16)b;
  unsigned short ux = *(unsigned short*)&x, uy = *(unsigned short*)&y;
  return (unsigned int)ux | ((unsigned int)uy << 16);
}

// ================= bucketed CSR build (round-12, unchanged) =================

__global__ __launch_bounds__(256) void hist2d_kernel(const int* __restrict__ dst,
                                                     int* __restrict__ counts,
                                                     int E, int epc, int nbuk) {
  __shared__ int cnt[256];
  const int c = blockIdx.x;
  for (int i = threadIdx.x; i < nbuk; i += 256) cnt[i] = 0;
  __syncthreads();
  int lo = c * epc, hi = min(E, lo + epc);
  for (int e = lo + threadIdx.x; e < hi; e += 256)
    atomicAdd(&cnt[dst[e] >> BSH], 1);
  __syncthreads();
  for (int i = threadIdx.x; i < nbuk; i += 256)
    counts[i * NCHUNK + c] = cnt[i];
}

__global__ __launch_bounds__(256) void scan_chunks_kernel(int* __restrict__ counts,
                                                          int* __restrict__ buktot) {
  __shared__ int s[256];
  const int b = blockIdx.x, t = threadIdx.x;
  int v = counts[b * NCHUNK + t];
  s[t] = v;
  __syncthreads();
  for (int off = 1; off < 256; off <<= 1) {
    int a = (t >= off) ? s[t - off] : 0;
    __syncthreads();
    s[t] += a;
    __syncthreads();
  }
  counts[b * NCHUNK + t] = s[t] - v;
  if (t == 255) buktot[b] = s[255];
}

__global__ void scan_buckets_kernel(const int* __restrict__ buktot,
                                    int* __restrict__ bukbase, int nbuk) {
  if (blockIdx.x == 0 && threadIdx.x == 0) {
    int run = 0;
    for (int i = 0; i < nbuk; ++i) { bukbase[i] = run; run += buktot[i]; }
    bukbase[nbuk] = run;
  }
}

__global__ __launch_bounds__(256) void scatter_bucket_kernel(const int* __restrict__ src,
                                                             const int* __restrict__ dst,
                                                             const float* __restrict__ ewt,
                                                             const int* __restrict__ counts,
                                                             const int* __restrict__ bukbase,
                                                             int2* __restrict__ tmp,
                                                             int E, int epc, int nbuk) {
  __shared__ int cur[256];
  const int c = blockIdx.x;
  for (int i = threadIdx.x; i < nbuk; i += 256)
    cur[i] = bukbase[i] + counts[i * NCHUNK + c];
  __syncthreads();
  int lo = c * epc, hi = min(E, lo + epc);
  for (int e = lo + threadIdx.x; e < hi; e += 256) {
    int d = dst[e];
    int b = d >> BSH;
    int pos = atomicAdd(&cur[b], 1);
    tmp[pos] = make_int2(src[e] | ((d & 511) << 17), __float_as_int(sigm(ewt[e])));
  }
}

__global__ __launch_bounds__(256) void place_kernel(const int2* __restrict__ tmp,
                                                    const int* __restrict__ bukbase,
                                                    int2* __restrict__ edata,
                                                    int* __restrict__ offs,
                                                    int n, int nbuk) {
  __shared__ int cnt[512];
  __shared__ int loc[512];
  __shared__ int s[256];
  const int b = blockIdx.x, t = threadIdx.x;
  const int base = bukbase[b], end = bukbase[b + 1];
  const int nb0 = b << BSH;
  const int nn = min(512, n - nb0);
  for (int i = t; i < 512; i += 256) cnt[i] = 0;
  __syncthreads();
  for (int i = base + t; i < end; i += 256)
    atomicAdd(&cnt[((unsigned)tmp[i].x) >> 17], 1);
  __syncthreads();
  int a0 = cnt[2 * t], a1 = cnt[2 * t + 1];
  int ps = a0 + a1;
  s[t] = ps;
  __syncthreads();
  for (int off = 1; off < 256; off <<= 1) {
    int ad = (t >= off) ? s[t - off] : 0;
    __syncthreads();
    s[t] += ad;
    __syncthreads();
  }
  int ex = s[t] - ps;
  loc[2 * t] = ex;
  loc[2 * t + 1] = ex + a0;
  __syncthreads();
  for (int j = t; j < nn; j += 256) offs[nb0 + j] = base + loc[j];
  if (b == nbuk - 1 && t == 0) offs[n] = end;
  for (int i = t; i < 512; i += 256) cnt[i] = loc[i];
  __syncthreads();
  for (int i = base + t; i < end; i += 256) {
    int2 r = tmp[i];
    int dl = ((unsigned)r.x) >> 17;
    int pos = atomicAdd(&cnt[dl], 1);
    edata[base + pos] = make_int2(r.x & 0x1FFFF, r.y);
  }
}

// ---------------- pre-convert w to bf16, K padded 500->512 ----------------

__global__ __launch_bounds__(256) void prep_w_kernel(const float* __restrict__ w,
                                                     unsigned short* __restrict__ wh) {
  int i = blockIdx.x * 256 + threadIdx.x;     // over 64*512
  int d = i >> 9, k = i & 511;
  float f = (k < NFEAT) ? w[d * NFEAT + k] : 0.f;
  __bf16 b = (__bf16)f;
  wh[i] = *reinterpret_cast<unsigned short*>(&b);
}

// ---------------- GEMM1 (round-12 version): BM=64, BK=64, bf16 MFMA ----------

__global__ __launch_bounds__(256) void gemm1_kernel(const float* __restrict__ x,
                                                    const unsigned short* __restrict__ whg,
                                                    const float* __restrict__ bias,
                                                    const float* __restrict__ al,
                                                    const float* __restrict__ ar,
                                                    unsigned short* __restrict__ hb,
                                                    float* __restrict__ hl,
                                                    float* __restrict__ hr, int n) {
  __shared__ __bf16 Ah[64][68], Bh[64][68];
  const int tid  = threadIdx.x;
  const int lane = tid & 63;
  const int wv   = tid >> 6;
  const int m0   = blockIdx.x * 64;
  const int r    = lane & 15;
  const int koff = (lane >> 4) * 8;
  const int rowA = wv * 16 + r;

  f32x4 acc[4];
#pragma unroll
  for (int c = 0; c < 4; ++c) acc[c] = (f32x4){0.f, 0.f, 0.f, 0.f};

  for (int kb = 0; kb < 512; kb += 64) {
#pragma unroll
    for (int rr = 0; rr < 4; ++rr) {
      int idx = rr * 256 + tid;
      int m   = idx >> 4;             // 0..63
      int k4  = (idx & 15) << 2;      // 0,4,...,60
      int gk  = kb + k4;
      int gm  = m0 + m;
      float4 va = {0.f, 0.f, 0.f, 0.f};
      if (gm < n && gk < NFEAT)
        va = *reinterpret_cast<const float4*>(&x[(size_t)gm * NFEAT + gk]);
      *reinterpret_cast<uint2*>(&Ah[m][k4]) =
          make_uint2(packbf(va.x, va.y), packbf(va.z, va.w));
      *reinterpret_cast<uint2*>(&Bh[m][k4]) =
          *reinterpret_cast<const uint2*>(&whg[m * 512 + gk]);
    }
    __syncthreads();
#pragma unroll
    for (int ks = 0; ks < 2; ++ks) {
      int k0 = ks * 32 + koff;
      bf16x8 a = *reinterpret_cast<const bf16x8*>(&Ah[rowA][k0]);
#pragma unroll
      for (int c = 0; c < 4; ++c) {
        bf16x8 b = *reinterpret_cast<const bf16x8*>(&Bh[c * 16 + r][k0]);
        acc[c] = __builtin_amdgcn_mfma_f32_16x16x32_bf16(a, b, acc[c], 0, 0, 0);
      }
    }
    __syncthreads();
  }

  float rowa[4] = {0.f, 0.f, 0.f, 0.f};
  float rowb[4] = {0.f, 0.f, 0.f, 0.f};
#pragma unroll
  for (int c = 0; c < 4; ++c) {
    int col = c * 16 + r;
    float bv = bias[col], alc = al[col], arc = ar[col];
#pragma unroll
    for (int rr = 0; rr < 4; ++rr) {
      int gmo = m0 + wv * 16 + (lane >> 4) * 4 + rr;
      float v = acc[c][rr] + bv;
      v = v > 0.f ? v : 0.f;
      if (gmo < n) {
        __bf16 vb16 = (__bf16)v;
        hb[(size_t)gmo * DIM + col] = *reinterpret_cast<unsigned short*>(&vb16);
      }
      rowa[rr] = fmaf(v, alc, rowa[rr]);
      rowb[rr] = fmaf(v, arc, rowb[rr]);
    }
  }
#pragma unroll
  for (int rr = 0; rr < 4; ++rr) {
    float a = rowa[rr], b = rowb[rr];
#pragma unroll
    for (int off = 8; off > 0; off >>= 1) {
      a += __shfl_xor(a, off, 64);
      b += __shfl_xor(b, off, 64);
    }
    if (r == 0) {
      int gmo = m0 + wv * 16 + (lane >> 4) * 4 + rr;
      if (gmo < n) { hl[gmo] = a; hr[gmo] = b; }
    }
  }
}

// ---------------- 8-stream edge loop (round-12) ----------------

#define EDGE_LOOP(READ_ED)                                                   \
  for (int j = 0; j < mcnt; j += 8) {                                        \
    _Pragma("unroll")                                                        \
    for (int u = 0; u < 8; ++u) {                                            \
      int idx = j + u;                                                       \
      bool valid = idx < cnt;                                                \
      int ci = valid ? s + idx : 0;                                          \
      int2 ed = READ_ED(ci);                                                 \
      int off = valid ? ed.x : 0;                                            \
      float cf = valid ? __int_as_float(ed.y) : 0.f;                         \
      uint4 hv = *reinterpret_cast<const uint4*>((const char*)hb + off + q16);\
      acc0 = fmaf(cf, bflo(hv.x), acc0); acc1 = fmaf(cf, bfhi(hv.x), acc1);  \
      acc2 = fmaf(cf, bflo(hv.y), acc2); acc3 = fmaf(cf, bfhi(hv.y), acc3);  \
      acc4 = fmaf(cf, bflo(hv.z), acc4); acc5 = fmaf(cf, bfhi(hv.z), acc5);  \
      acc6 = fmaf(cf, bflo(hv.w), acc6); acc7 = fmaf(cf, bfhi(hv.w), acc7);  \
    }                                                                        \
  }
#define RD_LDS(ci) eds[ci]
#define RD_GLB(ci) ({ int2 _e = edata[e0 + (ci)];                            \
      float _c = fast_tanh(hlv[_e.x] + hrd) * __int_as_float(_e.y);          \
      make_int2(_e.x * 128, __float_as_int(_c)); })

#define STAGE_EDGES(HLV, HRL)                                                \
  for (int i = tid; i < nE && i < LDSE; i += 256) {                          \
    int2 e = edata[e0 + i];                                                  \
    int key = e0 + i;                                                        \
    int nd = 0;                                                              \
    _Pragma("unroll")                                                        \
    for (int st = 16; st >= 1; st >>= 1)                                     \
      if (offs_l[nd + st] <= key) nd += st;                                  \
    float c = fast_tanh(HLV[e.x] + HRL[nd]) * __int_as_float(e.y);           \
    eds[i] = make_int2(e.x * 128, __float_as_int(c));                        \
  }

#define AGG_PROLOGUE()                                                       \
  const int tid  = threadIdx.x;                                              \
  const int lane = tid & 63;                                                 \
  const int wv   = tid >> 6;                                                 \
  const int g    = lane >> 3;          /* group 0..7 -> node */              \
  const int q    = lane & 7;           /* dim octet */                       \
  const int q16  = q << 4;                                                   \
  const int n0   = blockIdx.x * NPB;                                         \
  if (tid <= NPB) {                                                          \
    int nd = n0 + tid;                                                       \
    offs_l[tid] = offs[nd < n ? nd : n];                                     \
  }                                                                          \
  if (tid < NPB) {                                                           \
    int nd = n0 + tid;                                                       \
    hr_l[tid] = nd < n ? hrv[nd] : 0.f;                                      \
  }

#define AGG_SETUP()                                                          \
  const int e0 = offs_l[0];                                                  \
  const int nE = offs_l[NPB] - e0;                                           \
  STAGE_EDGES(hlv, hr_l)                                                     \
  __syncthreads();                                                           \
  const int node = n0 + wv * 8 + g;                                          \
  int s = 0, cnt = 0;                                                        \
  float hrd = 0.f;                                                           \
  if (node < n) {                                                            \
    s = offs_l[wv * 8 + g] - e0;                                             \
    cnt = offs_l[wv * 8 + g + 1] - e0 - s;                                   \
    hrd = hr_l[wv * 8 + g];                                                  \
  }                                                                          \
  int mcnt = cnt;                                                            \
  mcnt = max(mcnt, __shfl_xor(mcnt, 8, 64));                                 \
  mcnt = max(mcnt, __shfl_xor(mcnt, 16, 64));                                \
  mcnt = max(mcnt, __shfl_xor(mcnt, 32, 64));

// ---------------- FAConv layer-1 agg + fused layer-2 dots (round-12) ----------

__global__ __launch_bounds__(256) void agg1_kernel(const unsigned short* __restrict__ hb,
                                                   const int2* __restrict__ edata,
                                                   const int* __restrict__ offs,
                                                   const float* __restrict__ hlv,
                                                   const float* __restrict__ hrv,
                                                   const float* __restrict__ al2,
                                                   const float* __restrict__ ar2,
                                                   unsigned short* __restrict__ h1b,
                                                   float* __restrict__ hl2,
                                                   float* __restrict__ hr2, int n) {
  __shared__ int2 eds[LDSE];
  __shared__ int offs_l[NPB + 1];
  __shared__ float hr_l[NPB];
  AGG_PROLOGUE()
  __syncthreads();
  AGG_SETUP()
  float acc0 = 0.f, acc1 = 0.f, acc2 = 0.f, acc3 = 0.f;
  float acc4 = 0.f, acc5 = 0.f, acc6 = 0.f, acc7 = 0.f;
  if (nE <= LDSE) { EDGE_LOOP(RD_LDS) } else { EDGE_LOOP(RD_GLB) }

  if (node < n) {
    uint4 rv = *reinterpret_cast<const uint4*>((const char*)hb + (size_t)node * 128 + q16);
    float v0 = fmaf(EPS_FA, bflo(rv.x), acc0);
    float v1 = fmaf(EPS_FA, bfhi(rv.x), acc1);
    float v2 = fmaf(EPS_FA, bflo(rv.y), acc2);
    float v3 = fmaf(EPS_FA, bfhi(rv.y), acc3);
    float v4 = fmaf(EPS_FA, bflo(rv.z), acc4);
    float v5 = fmaf(EPS_FA, bfhi(rv.z), acc5);
    float v6 = fmaf(EPS_FA, bflo(rv.w), acc6);
    float v7 = fmaf(EPS_FA, bfhi(rv.w), acc7);
    uint4 pk = make_uint4(packbf(v0, v1), packbf(v2, v3), packbf(v4, v5), packbf(v6, v7));
    *reinterpret_cast<uint4*>((char*)h1b + (size_t)node * 128 + q16) = pk;
    const float4 ala = *reinterpret_cast<const float4*>(al2 + q * 8);
    const float4 alb = *reinterpret_cast<const float4*>(al2 + q * 8 + 4);
    const float4 ara = *reinterpret_cast<const float4*>(ar2 + q * 8);
    const float4 arb = *reinterpret_cast<const float4*>(ar2 + q * 8 + 4);
    float a = v0 * ala.x + v1 * ala.y + v2 * ala.z + v3 * ala.w
            + v4 * alb.x + v5 * alb.y + v6 * alb.z + v7 * alb.w;
    float b = v0 * ara.x + v1 * ara.y + v2 * ara.z + v3 * ara.w
            + v4 * arb.x + v5 * arb.y + v6 * arb.z + v7 * arb.w;
#pragma unroll
    for (int off = 4; off > 0; off >>= 1) {
      a += __shfl_xor(a, off, 64);
      b += __shfl_xor(b, off, 64);
    }
    if (q == 0) { hl2[node] = a; hr2[node] = b; }
  }
}

// ---------------- layer-2 agg + classifier — DIAGNOSTIC x4 edge loop ----------
// reps 0..2 are discarded (asm sink keeps them live); rep 3 = real result.
// Output bit-identical to round 12; dispatch duration ~4x the edge loop.

__global__ __launch_bounds__(256) void agg_cls_kernel(const unsigned short* __restrict__ hb,
                                                      const unsigned short* __restrict__ rawb,
                                                      const int2* __restrict__ edata,
                                                      const int* __restrict__ offs,
                                                      const float* __restrict__ hlv,
                                                      const float* __restrict__ hrv,
                                                      const float* __restrict__ t2w,
                                                      const float* __restrict__ t2b,
                                                      float* __restrict__ out, int n) {
  __shared__ int2 eds[LDSE];
  __shared__ int offs_l[NPB + 1];
  __shared__ float hr_l[NPB];
  __shared__ float t2s[DIM * NCLS];     // [k][cls]
  __shared__ float rowbuf[NPB][DIM];
  AGG_PROLOGUE()
  for (int i = tid; i < DIM * NCLS; i += 256) {
    int k = i / NCLS, cls = i - k * NCLS;
    t2s[i] = t2w[cls * DIM + k];
  }
  __syncthreads();
  AGG_SETUP()
  float acc0, acc1, acc2, acc3, acc4, acc5, acc6, acc7;
  for (int rep = 0; rep < 4; ++rep) {
    acc0 = acc1 = acc2 = acc3 = acc4 = acc5 = acc6 = acc7 = 0.f;
    if (nE <= LDSE) { EDGE_LOOP(RD_LDS) } else { EDGE_LOOP(RD_GLB) }
    if (rep < 3)
      asm volatile("" :: "v"(acc0), "v"(acc1), "v"(acc2), "v"(acc3),
                         "v"(acc4), "v"(acc5), "v"(acc6), "v"(acc7));
  }

  if (node >= n) return;
  const int nl = wv * 8 + g;
  {
    uint4 rv = *reinterpret_cast<const uint4*>((const char*)rawb + (size_t)node * 128 + q16);
    float4 va, vb;
    va.x = fmaf(EPS_FA, bflo(rv.x), acc0);
    va.y = fmaf(EPS_FA, bfhi(rv.x), acc1);
    va.z = fmaf(EPS_FA, bflo(rv.y), acc2);
    va.w = fmaf(EPS_FA, bfhi(rv.y), acc3);
    vb.x = fmaf(EPS_FA, bflo(rv.z), acc4);
    vb.y = fmaf(EPS_FA, bfhi(rv.z), acc5);
    vb.z = fmaf(EPS_FA, bflo(rv.w), acc6);
    vb.w = fmaf(EPS_FA, bfhi(rv.w), acc7);
    *reinterpret_cast<float4*>(&rowbuf[nl][q * 8])     = va;  // wave-local
    *reinterpret_cast<float4*>(&rowbuf[nl][q * 8 + 4]) = vb;
  }
  float lg[5];
#pragma unroll
  for (int j = 0; j < 5; ++j) lg[j] = t2b[q + 8 * j];
#pragma unroll
  for (int k = 0; k < DIM; ++k) {
    float rr = rowbuf[nl][k];
#pragma unroll
    for (int j = 0; j < 5; ++j)
      lg[j] = fmaf(rr, t2s[k * NCLS + q + 8 * j], lg[j]);
  }
  float mx = lg[0];
#pragma unroll
  for (int j = 1; j < 5; ++j) mx = fmaxf(mx, lg[j]);
#pragma unroll
  for (int off = 4; off > 0; off >>= 1) mx = fmaxf(mx, __shfl_xor(mx, off, 64));
  float ssum = 0.f;
#pragma unroll
  for (int j = 0; j < 5; ++j) ssum += __expf(lg[j] - mx);
#pragma unroll
  for (int off = 4; off > 0; off >>= 1) ssum += __shfl_xor(ssum, off, 64);
  float lse = mx + __logf(ssum);
  float* op = out + (size_t)node * NCLS;
#pragma unroll
  for (int j = 0; j < 5; ++j) op[q + 8 * j] = lg[j] - lse;
}

// ---------------- launch ----------------

extern "C" void kernel_launch(void* const* d_in, const int* in_sizes, int n_in,
                              void* d_out, int out_size, void* d_ws, size_t ws_size,
                              hipStream_t stream) {
  const float* x   = (const float*)d_in[0];
  const int*   ei  = (const int*)d_in[1];
  const float* ewt = (const float*)d_in[2];
  const float* t1w = (const float*)d_in[3];
  const float* t1b = (const float*)d_in[4];
  const float* al1 = (const float*)d_in[5];
  const float* ar1 = (const float*)d_in[6];
  const float* al2 = (const float*)d_in[7];
  const float* ar2 = (const float*)d_in[8];
  const float* t2w = (const float*)d_in[9];
  const float* t2b = (const float*)d_in[10];
  float* out = (float*)d_out;

  const int n = in_sizes[0] / NFEAT;   // 100000
  const int E = in_sizes[2];           // 1600000
  const int* srcp = ei;
  const int* dstp = ei + E;

  char* p = (char*)d_ws;
  auto alloc = [&](size_t bytes) {
    char* q = p;
    p += (bytes + 255) & ~(size_t)255;
    return q;
  };
  unsigned short* h0b = (unsigned short*)alloc((size_t)n * DIM * 2);
  unsigned short* h1b = (unsigned short*)alloc((size_t)n * DIM * 2);
  float* hl    = (float*)alloc((size_t)n * 4);
  float* hr    = (float*)alloc((size_t)n * 4);
  float* hl2   = (float*)alloc((size_t)n * 4);
  float* hr2   = (float*)alloc((size_t)n * 4);
  int*   offs  = (int*)alloc((size_t)(n + 1) * 4);
  int2*  edata = (int2*)alloc((size_t)E * 8);
  int2*  tmp   = (int2*)alloc((size_t)E * 8);
  unsigned short* whg = (unsigned short*)alloc((size_t)DIM * 512 * 2);
  int*   counts = (int*)alloc((size_t)256 * NCHUNK * 4);
  int*   buktot = (int*)alloc(256 * 4);
  int*   bukbase= (int*)alloc(257 * 4);

  const int nbuk = (n + 511) >> BSH;                 // 196
  const int epc  = (E + NCHUNK - 1) / NCHUNK;        // 6250

  hist2d_kernel<<<NCHUNK, 256, 0, stream>>>(dstp, counts, E, epc, nbuk);
  scan_chunks_kernel<<<nbuk, 256, 0, stream>>>(counts, buktot);
  scan_buckets_kernel<<<1, 64, 0, stream>>>(buktot, bukbase, nbuk);
  scatter_bucket_kernel<<<NCHUNK, 256, 0, stream>>>(srcp, dstp, ewt, counts, bukbase,
                                                    tmp, E, epc, nbuk);
  place_kernel<<<nbuk, 256, 0, stream>>>(tmp, bukbase, edata, offs, n, nbuk);

  prep_w_kernel<<<(DIM * 512) / 256, 256, 0, stream>>>(t1w, whg);
  gemm1_kernel<<<(n + 63) / 64, 256, 0, stream>>>(x, whg, t1b, al1, ar1,
                                                  h0b, hl, hr, n);

  const int ab = (n + NPB - 1) / NPB;
  agg1_kernel<<<ab, 256, 0, stream>>>(h0b, edata, offs, hl, hr, al2, ar2, h1b, hl2, hr2, n);
  agg_cls_kernel<<<ab, 256, 0, stream>>>(h1b, h0b, edata, offs, hl2, hr2, t2w, t2b, out, n);
}

// Round 16
// 231.312 us; speedup vs baseline: 1.1912x; 1.1912x over previous
//
#include <hip/hip_runtime.h>
#include <hip/hip_bf16.h>

#define NFEAT 500
#define DIM   64
#define NCLS  40
#define EPS_FA 0.3f
#define NPB   32      // nodes per agg block (4 waves x 8 groups)
#define LDSE  1024    // staged edges per block (mean 512)
#define NCHUNK 256    // edge chunks for bucket partition
#define BSH   9       // bucket = 512 nodes

typedef __attribute__((ext_vector_type(8))) __bf16 bf16x8;
typedef __attribute__((ext_vector_type(4))) float  f32x4;

__device__ __forceinline__ float bflo(unsigned int u) {
  return __uint_as_float(u << 16);
}
__device__ __forceinline__ float bfhi(unsigned int u) {
  return __uint_as_float(u & 0xffff0000u);
}
__device__ __forceinline__ float fast_tanh(float x) {
  return 1.f - 2.f / (__expf(2.f * x) + 1.f);
}
__device__ __forceinline__ float sigm(float w) {
  return (__builtin_fabsf(w) > 0.f) ? (1.f / (1.f + __expf(-w))) : 0.f;
}
__device__ __forceinline__ unsigned int packbf(float a, float b) {
  __bf16 x = (__bf16)a, y = (__bf16)b;
  unsigned short ux = *(unsigned short*)&x, uy = *(unsigned short*)&y;
  return (unsigned int)ux | ((unsigned int)uy << 16);
}

// ================= bucketed CSR build (round-12, unchanged) =================

__global__ __launch_bounds__(256) void hist2d_kernel(const int* __restrict__ dst,
                                                     int* __restrict__ counts,
                                                     int E, int epc, int nbuk) {
  __shared__ int cnt[256];
  const int c = blockIdx.x;
  for (int i = threadIdx.x; i < nbuk; i += 256) cnt[i] = 0;
  __syncthreads();
  int lo = c * epc, hi = min(E, lo + epc);
  for (int e = lo + threadIdx.x; e < hi; e += 256)
    atomicAdd(&cnt[dst[e] >> BSH], 1);
  __syncthreads();
  for (int i = threadIdx.x; i < nbuk; i += 256)
    counts[i * NCHUNK + c] = cnt[i];
}

__global__ __launch_bounds__(256) void scan_chunks_kernel(int* __restrict__ counts,
                                                          int* __restrict__ buktot) {
  __shared__ int s[256];
  const int b = blockIdx.x, t = threadIdx.x;
  int v = counts[b * NCHUNK + t];
  s[t] = v;
  __syncthreads();
  for (int off = 1; off < 256; off <<= 1) {
    int a = (t >= off) ? s[t - off] : 0;
    __syncthreads();
    s[t] += a;
    __syncthreads();
  }
  counts[b * NCHUNK + t] = s[t] - v;
  if (t == 255) buktot[b] = s[255];
}

__global__ void scan_buckets_kernel(const int* __restrict__ buktot,
                                    int* __restrict__ bukbase, int nbuk) {
  if (blockIdx.x == 0 && threadIdx.x == 0) {
    int run = 0;
    for (int i = 0; i < nbuk; ++i) { bukbase[i] = run; run += buktot[i]; }
    bukbase[nbuk] = run;
  }
}

__global__ __launch_bounds__(256) void scatter_bucket_kernel(const int* __restrict__ src,
                                                             const int* __restrict__ dst,
                                                             const float* __restrict__ ewt,
                                                             const int* __restrict__ counts,
                                                             const int* __restrict__ bukbase,
                                                             int2* __restrict__ tmp,
                                                             int E, int epc, int nbuk) {
  __shared__ int cur[256];
  const int c = blockIdx.x;
  for (int i = threadIdx.x; i < nbuk; i += 256)
    cur[i] = bukbase[i] + counts[i * NCHUNK + c];
  __syncthreads();
  int lo = c * epc, hi = min(E, lo + epc);
  for (int e = lo + threadIdx.x; e < hi; e += 256) {
    int d = dst[e];
    int b = d >> BSH;
    int pos = atomicAdd(&cur[b], 1);
    tmp[pos] = make_int2(src[e] | ((d & 511) << 17), __float_as_int(sigm(ewt[e])));
  }
}

__global__ __launch_bounds__(256) void place_kernel(const int2* __restrict__ tmp,
                                                    const int* __restrict__ bukbase,
                                                    int2* __restrict__ edata,
                                                    int* __restrict__ offs,
                                                    int n, int nbuk) {
  __shared__ int cnt[512];
  __shared__ int loc[512];
  __shared__ int s[256];
  const int b = blockIdx.x, t = threadIdx.x;
  const int base = bukbase[b], end = bukbase[b + 1];
  const int nb0 = b << BSH;
  const int nn = min(512, n - nb0);
  for (int i = t; i < 512; i += 256) cnt[i] = 0;
  __syncthreads();
  for (int i = base + t; i < end; i += 256)
    atomicAdd(&cnt[((unsigned)tmp[i].x) >> 17], 1);
  __syncthreads();
  int a0 = cnt[2 * t], a1 = cnt[2 * t + 1];
  int ps = a0 + a1;
  s[t] = ps;
  __syncthreads();
  for (int off = 1; off < 256; off <<= 1) {
    int ad = (t >= off) ? s[t - off] : 0;
    __syncthreads();
    s[t] += ad;
    __syncthreads();
  }
  int ex = s[t] - ps;
  loc[2 * t] = ex;
  loc[2 * t + 1] = ex + a0;
  __syncthreads();
  for (int j = t; j < nn; j += 256) offs[nb0 + j] = base + loc[j];
  if (b == nbuk - 1 && t == 0) offs[n] = end;
  for (int i = t; i < 512; i += 256) cnt[i] = loc[i];
  __syncthreads();
  for (int i = base + t; i < end; i += 256) {
    int2 r = tmp[i];
    int dl = ((unsigned)r.x) >> 17;
    int pos = atomicAdd(&cnt[dl], 1);
    edata[base + pos] = make_int2(r.x & 0x1FFFF, r.y);
  }
}

// ---------------- pre-convert w to bf16, K padded 500->512 ----------------

__global__ __launch_bounds__(256) void prep_w_kernel(const float* __restrict__ w,
                                                     unsigned short* __restrict__ wh) {
  int i = blockIdx.x * 256 + threadIdx.x;     // over 64*512
  int d = i >> 9, k = i & 511;
  float f = (k < NFEAT) ? w[d * NFEAT + k] : 0.f;
  __bf16 b = (__bf16)f;
  wh[i] = *reinterpret_cast<unsigned short*>(&b);
}

// ---------------- GEMM1: BM=64, BK=64, bf16 MFMA, T14 async-split staging ------
// Loads for tile kb+1 issue BEFORE MFMA(kb): HBM latency hides under compute.
// Single LDS buffer (17.4 KB) keeps 8 blocks/CU.

__global__ __launch_bounds__(256) void gemm1_kernel(const float* __restrict__ x,
                                                    const unsigned short* __restrict__ whg,
                                                    const float* __restrict__ bias,
                                                    const float* __restrict__ al,
                                                    const float* __restrict__ ar,
                                                    unsigned short* __restrict__ hb,
                                                    float* __restrict__ hl,
                                                    float* __restrict__ hr, int n) {
  __shared__ __bf16 Ah[64][68], Bh[64][68];
  const int tid  = threadIdx.x;
  const int lane = tid & 63;
  const int wv   = tid >> 6;
  const int m0   = blockIdx.x * 64;
  const int r    = lane & 15;
  const int koff = (lane >> 4) * 8;
  const int rowA = wv * 16 + r;

  // per-thread staging geometry (constant across K)
  int mm[4], kk4[4];
  bool mok[4];
  const float* ap[4];
  const unsigned short* bp[4];
#pragma unroll
  for (int rr = 0; rr < 4; ++rr) {
    int idx = rr * 256 + tid;
    mm[rr]  = idx >> 4;              // 0..63
    kk4[rr] = (idx & 15) << 2;       // 0..60
    int gm = m0 + mm[rr];
    mok[rr] = gm < n;
    ap[rr] = x + (size_t)(mok[rr] ? gm : 0) * NFEAT + kk4[rr];
    bp[rr] = whg + mm[rr] * 512 + kk4[rr];
  }

  f32x4 acc[4];
#pragma unroll
  for (int c = 0; c < 4; ++c) acc[c] = (f32x4){0.f, 0.f, 0.f, 0.f};

  float4 areg[4];
  uint2  breg[4];

#define LOADK(KB)                                                            \
  _Pragma("unroll")                                                          \
  for (int rr = 0; rr < 4; ++rr) {                                           \
    bool v = mok[rr] && ((KB) + kk4[rr] < NFEAT);                            \
    areg[rr] = v ? *reinterpret_cast<const float4*>(ap[rr] + (KB))           \
                 : (float4){0.f, 0.f, 0.f, 0.f};                             \
    breg[rr] = *reinterpret_cast<const uint2*>(bp[rr] + (KB));               \
  }
#define WRITEK()                                                             \
  _Pragma("unroll")                                                          \
  for (int rr = 0; rr < 4; ++rr) {                                           \
    *reinterpret_cast<uint2*>(&Ah[mm[rr]][kk4[rr]]) =                        \
        make_uint2(packbf(areg[rr].x, areg[rr].y),                           \
                   packbf(areg[rr].z, areg[rr].w));                          \
    *reinterpret_cast<uint2*>(&Bh[mm[rr]][kk4[rr]]) = breg[rr];              \
  }

  LOADK(0)
  WRITEK()
  __syncthreads();

  for (int kb = 0; kb < 512; kb += 64) {
    if (kb + 64 < 512) LOADK(kb + 64)        // issue next-tile loads early
#pragma unroll
    for (int ks = 0; ks < 2; ++ks) {
      int k0 = ks * 32 + koff;
      bf16x8 a = *reinterpret_cast<const bf16x8*>(&Ah[rowA][k0]);
#pragma unroll
      for (int c = 0; c < 4; ++c) {
        bf16x8 b = *reinterpret_cast<const bf16x8*>(&Bh[c * 16 + r][k0]);
        acc[c] = __builtin_amdgcn_mfma_f32_16x16x32_bf16(a, b, acc[c], 0, 0, 0);
      }
    }
    __syncthreads();                          // all waves done reading LDS
    if (kb + 64 < 512) {
      WRITEK()
      __syncthreads();                        // next tile visible
    }
  }
#undef LOADK
#undef WRITEK

  float rowa[4] = {0.f, 0.f, 0.f, 0.f};
  float rowb[4] = {0.f, 0.f, 0.f, 0.f};
#pragma unroll
  for (int c = 0; c < 4; ++c) {
    int col = c * 16 + r;
    float bv = bias[col], alc = al[col], arc = ar[col];
#pragma unroll
    for (int rr = 0; rr < 4; ++rr) {
      int gmo = m0 + wv * 16 + (lane >> 4) * 4 + rr;
      float v = acc[c][rr] + bv;
      v = v > 0.f ? v : 0.f;
      if (gmo < n) {
        __bf16 vb16 = (__bf16)v;
        hb[(size_t)gmo * DIM + col] = *reinterpret_cast<unsigned short*>(&vb16);
      }
      rowa[rr] = fmaf(v, alc, rowa[rr]);
      rowb[rr] = fmaf(v, arc, rowb[rr]);
    }
  }
#pragma unroll
  for (int rr = 0; rr < 4; ++rr) {
    float a = rowa[rr], b = rowb[rr];
#pragma unroll
    for (int off = 8; off > 0; off >>= 1) {
      a += __shfl_xor(a, off, 64);
      b += __shfl_xor(b, off, 64);
    }
    if (r == 0) {
      int gmo = m0 + wv * 16 + (lane >> 4) * 4 + rr;
      if (gmo < n) { hl[gmo] = a; hr[gmo] = b; }
    }
  }
}

// ---------------- 8-stream edge loop (round-12) ----------------

#define EDGE_LOOP(READ_ED)                                                   \
  for (int j = 0; j < mcnt; j += 8) {                                        \
    _Pragma("unroll")                                                        \
    for (int u = 0; u < 8; ++u) {                                            \
      int idx = j + u;                                                       \
      bool valid = idx < cnt;                                                \
      int ci = valid ? s + idx : 0;                                          \
      int2 ed = READ_ED(ci);                                                 \
      int off = valid ? ed.x : 0;                                            \
      float cf = valid ? __int_as_float(ed.y) : 0.f;                         \
      uint4 hv = *reinterpret_cast<const uint4*>((const char*)hb + off + q16);\
      acc0 = fmaf(cf, bflo(hv.x), acc0); acc1 = fmaf(cf, bfhi(hv.x), acc1);  \
      acc2 = fmaf(cf, bflo(hv.y), acc2); acc3 = fmaf(cf, bfhi(hv.y), acc3);  \
      acc4 = fmaf(cf, bflo(hv.z), acc4); acc5 = fmaf(cf, bfhi(hv.z), acc5);  \
      acc6 = fmaf(cf, bflo(hv.w), acc6); acc7 = fmaf(cf, bfhi(hv.w), acc7);  \
    }                                                                        \
  }
#define RD_LDS(ci) eds[ci]
#define RD_GLB(ci) ({ int2 _e = edata[e0 + (ci)];                            \
      float _c = fast_tanh(hlv[_e.x] + hrd) * __int_as_float(_e.y);          \
      make_int2(_e.x * 128, __float_as_int(_c)); })

#define STAGE_EDGES(HLV, HRL)                                                \
  for (int i = tid; i < nE && i < LDSE; i += 256) {                          \
    int2 e = edata[e0 + i];                                                  \
    int key = e0 + i;                                                        \
    int nd = 0;                                                              \
    _Pragma("unroll")                                                        \
    for (int st = 16; st >= 1; st >>= 1)                                     \
      if (offs_l[nd + st] <= key) nd += st;                                  \
    float c = fast_tanh(HLV[e.x] + HRL[nd]) * __int_as_float(e.y);           \
    eds[i] = make_int2(e.x * 128, __float_as_int(c));                        \
  }

#define AGG_PROLOGUE()                                                       \
  const int tid  = threadIdx.x;                                              \
  const int lane = tid & 63;                                                 \
  const int wv   = tid >> 6;                                                 \
  const int g    = lane >> 3;          /* group 0..7 -> node */              \
  const int q    = lane & 7;           /* dim octet */                       \
  const int q16  = q << 4;                                                   \
  const int n0   = blockIdx.x * NPB;                                         \
  if (tid <= NPB) {                                                          \
    int nd = n0 + tid;                                                       \
    offs_l[tid] = offs[nd < n ? nd : n];                                     \
  }                                                                          \
  if (tid < NPB) {                                                           \
    int nd = n0 + tid;                                                       \
    hr_l[tid] = nd < n ? hrv[nd] : 0.f;                                      \
  }

#define AGG_BODY()                                                           \
  const int e0 = offs_l[0];                                                  \
  const int nE = offs_l[NPB] - e0;                                           \
  STAGE_EDGES(hlv, hr_l)                                                     \
  __syncthreads();                                                           \
  const int node = n0 + wv * 8 + g;                                          \
  int s = 0, cnt = 0;                                                        \
  float hrd = 0.f;                                                           \
  if (node < n) {                                                            \
    s = offs_l[wv * 8 + g] - e0;                                             \
    cnt = offs_l[wv * 8 + g + 1] - e0 - s;                                   \
    hrd = hr_l[wv * 8 + g];                                                  \
  }                                                                          \
  int mcnt = cnt;                                                            \
  mcnt = max(mcnt, __shfl_xor(mcnt, 8, 64));                                 \
  mcnt = max(mcnt, __shfl_xor(mcnt, 16, 64));                                \
  mcnt = max(mcnt, __shfl_xor(mcnt, 32, 64));                                \
  float acc0 = 0.f, acc1 = 0.f, acc2 = 0.f, acc3 = 0.f;                      \
  float acc4 = 0.f, acc5 = 0.f, acc6 = 0.f, acc7 = 0.f;                      \
  if (nE <= LDSE) { EDGE_LOOP(RD_LDS) } else { EDGE_LOOP(RD_GLB) }

// ---------------- FAConv layer-1 agg + fused layer-2 dots ----------------

__global__ __launch_bounds__(256) void agg1_kernel(const unsigned short* __restrict__ hb,
                                                   const int2* __restrict__ edata,
                                                   const int* __restrict__ offs,
                                                   const float* __restrict__ hlv,
                                                   const float* __restrict__ hrv,
                                                   const float* __restrict__ al2,
                                                   const float* __restrict__ ar2,
                                                   unsigned short* __restrict__ h1b,
                                                   float* __restrict__ hl2,
                                                   float* __restrict__ hr2, int n) {
  __shared__ int2 eds[LDSE];
  __shared__ int offs_l[NPB + 1];
  __shared__ float hr_l[NPB];
  AGG_PROLOGUE()
  __syncthreads();
  AGG_BODY()

  if (node < n) {
    uint4 rv = *reinterpret_cast<const uint4*>((const char*)hb + (size_t)node * 128 + q16);
    float v0 = fmaf(EPS_FA, bflo(rv.x), acc0);
    float v1 = fmaf(EPS_FA, bfhi(rv.x), acc1);
    float v2 = fmaf(EPS_FA, bflo(rv.y), acc2);
    float v3 = fmaf(EPS_FA, bfhi(rv.y), acc3);
    float v4 = fmaf(EPS_FA, bflo(rv.z), acc4);
    float v5 = fmaf(EPS_FA, bfhi(rv.z), acc5);
    float v6 = fmaf(EPS_FA, bflo(rv.w), acc6);
    float v7 = fmaf(EPS_FA, bfhi(rv.w), acc7);
    uint4 pk = make_uint4(packbf(v0, v1), packbf(v2, v3), packbf(v4, v5), packbf(v6, v7));
    *reinterpret_cast<uint4*>((char*)h1b + (size_t)node * 128 + q16) = pk;
    const float4 ala = *reinterpret_cast<const float4*>(al2 + q * 8);
    const float4 alb = *reinterpret_cast<const float4*>(al2 + q * 8 + 4);
    const float4 ara = *reinterpret_cast<const float4*>(ar2 + q * 8);
    const float4 arb = *reinterpret_cast<const float4*>(ar2 + q * 8 + 4);
    float a = v0 * ala.x + v1 * ala.y + v2 * ala.z + v3 * ala.w
            + v4 * alb.x + v5 * alb.y + v6 * alb.z + v7 * alb.w;
    float b = v0 * ara.x + v1 * ara.y + v2 * ara.z + v3 * ara.w
            + v4 * arb.x + v5 * arb.y + v6 * arb.z + v7 * arb.w;
#pragma unroll
    for (int off = 4; off > 0; off >>= 1) {
      a += __shfl_xor(a, off, 64);
      b += __shfl_xor(b, off, 64);
    }
    if (q == 0) { hl2[node] = a; hr2[node] = b; }
  }
}

// ---------------- layer-2 agg fused with classifier + log_softmax ----------------
// rowbuf padded to 68 floats/row: classifier broadcast reads spread across banks.

__global__ __launch_bounds__(256) void agg_cls_kernel(const unsigned short* __restrict__ hb,
                                                      const unsigned short* __restrict__ rawb,
                                                      const int2* __restrict__ edata,
                                                      const int* __restrict__ offs,
                                                      const float* __restrict__ hlv,
                                                      const float* __restrict__ hrv,
                                                      const float* __restrict__ t2w,
                                                      const float* __restrict__ t2b,
                                                      float* __restrict__ out, int n) {
  __shared__ int2 eds[LDSE];
  __shared__ int offs_l[NPB + 1];
  __shared__ float hr_l[NPB];
  __shared__ float t2s[DIM * NCLS];     // [k][cls]
  __shared__ float rowbuf[NPB][68];     // +4 pad: bank = (4*nl + k) % 32, conflict-free
  AGG_PROLOGUE()
  for (int i = tid; i < DIM * NCLS; i += 256) {
    int k = i / NCLS, cls = i - k * NCLS;
    t2s[i] = t2w[cls * DIM + k];
  }
  __syncthreads();
  AGG_BODY()

  if (node >= n) return;
  const int nl = wv * 8 + g;
  {
    uint4 rv = *reinterpret_cast<const uint4*>((const char*)rawb + (size_t)node * 128 + q16);
    float4 va, vb;
    va.x = fmaf(EPS_FA, bflo(rv.x), acc0);
    va.y = fmaf(EPS_FA, bfhi(rv.x), acc1);
    va.z = fmaf(EPS_FA, bflo(rv.y), acc2);
    va.w = fmaf(EPS_FA, bfhi(rv.y), acc3);
    vb.x = fmaf(EPS_FA, bflo(rv.z), acc4);
    vb.y = fmaf(EPS_FA, bfhi(rv.z), acc5);
    vb.z = fmaf(EPS_FA, bflo(rv.w), acc6);
    vb.w = fmaf(EPS_FA, bfhi(rv.w), acc7);
    *reinterpret_cast<float4*>(&rowbuf[nl][q * 8])     = va;  // wave-local
    *reinterpret_cast<float4*>(&rowbuf[nl][q * 8 + 4]) = vb;
  }
  float lg[5];
#pragma unroll
  for (int j = 0; j < 5; ++j) lg[j] = t2b[q + 8 * j];
#pragma unroll
  for (int k = 0; k < DIM; ++k) {
    float rr = rowbuf[nl][k];
#pragma unroll
    for (int j = 0; j < 5; ++j)
      lg[j] = fmaf(rr, t2s[k * NCLS + q + 8 * j], lg[j]);
  }
  float mx = lg[0];
#pragma unroll
  for (int j = 1; j < 5; ++j) mx = fmaxf(mx, lg[j]);
#pragma unroll
  for (int off = 4; off > 0; off >>= 1) mx = fmaxf(mx, __shfl_xor(mx, off, 64));
  float ssum = 0.f;
#pragma unroll
  for (int j = 0; j < 5; ++j) ssum += __expf(lg[j] - mx);
#pragma unroll
  for (int off = 4; off > 0; off >>= 1) ssum += __shfl_xor(ssum, off, 64);
  float lse = mx + __logf(ssum);
  float* op = out + (size_t)node * NCLS;
#pragma unroll
  for (int j = 0; j < 5; ++j) op[q + 8 * j] = lg[j] - lse;
}

// ---------------- launch ----------------

extern "C" void kernel_launch(void* const* d_in, const int* in_sizes, int n_in,
                              void* d_out, int out_size, void* d_ws, size_t ws_size,
                              hipStream_t stream) {
  const float* x   = (const float*)d_in[0];
  const int*   ei  = (const int*)d_in[1];
  const float* ewt = (const float*)d_in[2];
  const float* t1w = (const float*)d_in[3];
  const float* t1b = (const float*)d_in[4];
  const float* al1 = (const float*)d_in[5];
  const float* ar1 = (const float*)d_in[6];
  const float* al2 = (const float*)d_in[7];
  const float* ar2 = (const float*)d_in[8];
  const float* t2w = (const float*)d_in[9];
  const float* t2b = (const float*)d_in[10];
  float* out = (float*)d_out;

  const int n = in_sizes[0] / NFEAT;   // 100000
  const int E = in_sizes[2];           // 1600000
  const int* srcp = ei;
  const int* dstp = ei + E;

  char* p = (char*)d_ws;
  auto alloc = [&](size_t bytes) {
    char* q = p;
    p += (bytes + 255) & ~(size_t)255;
    return q;
  };
  unsigned short* h0b = (unsigned short*)alloc((size_t)n * DIM * 2);
  unsigned short* h1b = (unsigned short*)alloc((size_t)n * DIM * 2);
  float* hl    = (float*)alloc((size_t)n * 4);
  float* hr    = (float*)alloc((size_t)n * 4);
  float* hl2   = (float*)alloc((size_t)n * 4);
  float* hr2   = (float*)alloc((size_t)n * 4);
  int*   offs  = (int*)alloc((size_t)(n + 1) * 4);
  int2*  edata = (int2*)alloc((size_t)E * 8);
  int2*  tmp   = (int2*)alloc((size_t)E * 8);
  unsigned short* whg = (unsigned short*)alloc((size_t)DIM * 512 * 2);
  int*   counts = (int*)alloc((size_t)256 * NCHUNK * 4);
  int*   buktot = (int*)alloc(256 * 4);
  int*   bukbase= (int*)alloc(257 * 4);

  const int nbuk = (n + 511) >> BSH;                 // 196
  const int epc  = (E + NCHUNK - 1) / NCHUNK;        // 6250

  hist2d_kernel<<<NCHUNK, 256, 0, stream>>>(dstp, counts, E, epc, nbuk);
  scan_chunks_kernel<<<nbuk, 256, 0, stream>>>(counts, buktot);
  scan_buckets_kernel<<<1, 64, 0, stream>>>(buktot, bukbase, nbuk);
  scatter_bucket_kernel<<<NCHUNK, 256, 0, stream>>>(srcp, dstp, ewt, counts, bukbase,
                                                    tmp, E, epc, nbuk);
  place_kernel<<<nbuk, 256, 0, stream>>>(tmp, bukbase, edata, offs, n, nbuk);

  prep_w_kernel<<<(DIM * 512) / 256, 256, 0, stream>>>(t1w, whg);
  gemm1_kernel<<<(n + 63) / 64, 256, 0, stream>>>(x, whg, t1b, al1, ar1,
                                                  h0b, hl, hr, n);

  const int ab = (n + NPB - 1) / NPB;
  agg1_kernel<<<ab, 256, 0, stream>>>(h0b, edata, offs, hl, hr, al2, ar2, h1b, hl2, hr2, n);
  agg_cls_kernel<<<ab, 256, 0, stream>>>(h1b, h0b, edata, offs, hl2, hr2, t2w, t2b, out, n);
}

// Round 17
// 224.728 us; speedup vs baseline: 1.2261x; 1.0293x over previous
//
#include <hip/hip_runtime.h>
#include <hip/hip_bf16.h>

#define NFEAT 500
#define DIM   64
#define NCLS  40
#define EPS_FA 0.3f
#define NPB   32      // nodes per agg block (4 waves x 8 groups)
#define LDSE  1024    // staged edges per block (mean 512)
#define NCHUNK 256    // edge chunks for bucket partition
#define BSH   9       // bucket = 512 nodes

typedef __attribute__((ext_vector_type(8))) __bf16 bf16x8;
typedef __attribute__((ext_vector_type(4))) float  f32x4;

__device__ __forceinline__ float bflo(unsigned int u) {
  return __uint_as_float(u << 16);
}
__device__ __forceinline__ float bfhi(unsigned int u) {
  return __uint_as_float(u & 0xffff0000u);
}
__device__ __forceinline__ float fast_tanh(float x) {
  return 1.f - 2.f / (__expf(2.f * x) + 1.f);
}
__device__ __forceinline__ float sigm(float w) {
  return (__builtin_fabsf(w) > 0.f) ? (1.f / (1.f + __expf(-w))) : 0.f;
}
__device__ __forceinline__ unsigned int packbf(float a, float b) {
  __bf16 x = (__bf16)a, y = (__bf16)b;
  unsigned short ux = *(unsigned short*)&x, uy = *(unsigned short*)&y;
  return (unsigned int)ux | ((unsigned int)uy << 16);
}

// ================= bucketed CSR build (round-12, unchanged) =================

__global__ __launch_bounds__(256) void hist2d_kernel(const int* __restrict__ dst,
                                                     int* __restrict__ counts,
                                                     int E, int epc, int nbuk) {
  __shared__ int cnt[256];
  const int c = blockIdx.x;
  for (int i = threadIdx.x; i < nbuk; i += 256) cnt[i] = 0;
  __syncthreads();
  int lo = c * epc, hi = min(E, lo + epc);
  for (int e = lo + threadIdx.x; e < hi; e += 256)
    atomicAdd(&cnt[dst[e] >> BSH], 1);
  __syncthreads();
  for (int i = threadIdx.x; i < nbuk; i += 256)
    counts[i * NCHUNK + c] = cnt[i];
}

__global__ __launch_bounds__(256) void scan_chunks_kernel(int* __restrict__ counts,
                                                          int* __restrict__ buktot) {
  __shared__ int s[256];
  const int b = blockIdx.x, t = threadIdx.x;
  int v = counts[b * NCHUNK + t];
  s[t] = v;
  __syncthreads();
  for (int off = 1; off < 256; off <<= 1) {
    int a = (t >= off) ? s[t - off] : 0;
    __syncthreads();
    s[t] += a;
    __syncthreads();
  }
  counts[b * NCHUNK + t] = s[t] - v;
  if (t == 255) buktot[b] = s[255];
}

__global__ void scan_buckets_kernel(const int* __restrict__ buktot,
                                    int* __restrict__ bukbase, int nbuk) {
  if (blockIdx.x == 0 && threadIdx.x == 0) {
    int run = 0;
    for (int i = 0; i < nbuk; ++i) { bukbase[i] = run; run += buktot[i]; }
    bukbase[nbuk] = run;
  }
}

__global__ __launch_bounds__(256) void scatter_bucket_kernel(const int* __restrict__ src,
                                                             const int* __restrict__ dst,
                                                             const float* __restrict__ ewt,
                                                             const int* __restrict__ counts,
                                                             const int* __restrict__ bukbase,
                                                             int2* __restrict__ tmp,
                                                             int E, int epc, int nbuk) {
  __shared__ int cur[256];
  const int c = blockIdx.x;
  for (int i = threadIdx.x; i < nbuk; i += 256)
    cur[i] = bukbase[i] + counts[i * NCHUNK + c];
  __syncthreads();
  int lo = c * epc, hi = min(E, lo + epc);
  for (int e = lo + threadIdx.x; e < hi; e += 256) {
    int d = dst[e];
    int b = d >> BSH;
    int pos = atomicAdd(&cur[b], 1);
    tmp[pos] = make_int2(src[e] | ((d & 511) << 17), __float_as_int(sigm(ewt[e])));
  }
}

__global__ __launch_bounds__(256) void place_kernel(const int2* __restrict__ tmp,
                                                    const int* __restrict__ bukbase,
                                                    int2* __restrict__ edata,
                                                    int* __restrict__ offs,
                                                    int n, int nbuk) {
  __shared__ int cnt[512];
  __shared__ int loc[512];
  __shared__ int s[256];
  const int b = blockIdx.x, t = threadIdx.x;
  const int base = bukbase[b], end = bukbase[b + 1];
  const int nb0 = b << BSH;
  const int nn = min(512, n - nb0);
  for (int i = t; i < 512; i += 256) cnt[i] = 0;
  __syncthreads();
  for (int i = base + t; i < end; i += 256)
    atomicAdd(&cnt[((unsigned)tmp[i].x) >> 17], 1);
  __syncthreads();
  int a0 = cnt[2 * t], a1 = cnt[2 * t + 1];
  int ps = a0 + a1;
  s[t] = ps;
  __syncthreads();
  for (int off = 1; off < 256; off <<= 1) {
    int ad = (t >= off) ? s[t - off] : 0;
    __syncthreads();
    s[t] += ad;
    __syncthreads();
  }
  int ex = s[t] - ps;
  loc[2 * t] = ex;
  loc[2 * t + 1] = ex + a0;
  __syncthreads();
  for (int j = t; j < nn; j += 256) offs[nb0 + j] = base + loc[j];
  if (b == nbuk - 1 && t == 0) offs[n] = end;
  for (int i = t; i < 512; i += 256) cnt[i] = loc[i];
  __syncthreads();
  for (int i = base + t; i < end; i += 256) {
    int2 r = tmp[i];
    int dl = ((unsigned)r.x) >> 17;
    int pos = atomicAdd(&cnt[dl], 1);
    edata[base + pos] = make_int2(r.x & 0x1FFFF, r.y);
  }
}

// ---------------- pre-convert w to bf16, K padded 500->512 ----------------

__global__ __launch_bounds__(256) void prep_w_kernel(const float* __restrict__ w,
                                                     unsigned short* __restrict__ wh) {
  int i = blockIdx.x * 256 + threadIdx.x;     // over 64*512
  int d = i >> 9, k = i & 511;
  float f = (k < NFEAT) ? w[d * NFEAT + k] : 0.f;
  __bf16 b = (__bf16)f;
  wh[i] = *reinterpret_cast<unsigned short*>(&b);
}

// ---------------- GEMM1 (round-12 version): BM=64, BK=64, bf16 MFMA ----------

__global__ __launch_bounds__(256) void gemm1_kernel(const float* __restrict__ x,
                                                    const unsigned short* __restrict__ whg,
                                                    const float* __restrict__ bias,
                                                    const float* __restrict__ al,
                                                    const float* __restrict__ ar,
                                                    unsigned short* __restrict__ hb,
                                                    float* __restrict__ hl,
                                                    float* __restrict__ hr, int n) {
  __shared__ __bf16 Ah[64][68], Bh[64][68];
  const int tid  = threadIdx.x;
  const int lane = tid & 63;
  const int wv   = tid >> 6;
  const int m0   = blockIdx.x * 64;
  const int r    = lane & 15;
  const int koff = (lane >> 4) * 8;
  const int rowA = wv * 16 + r;

  f32x4 acc[4];
#pragma unroll
  for (int c = 0; c < 4; ++c) acc[c] = (f32x4){0.f, 0.f, 0.f, 0.f};

  for (int kb = 0; kb < 512; kb += 64) {
#pragma unroll
    for (int rr = 0; rr < 4; ++rr) {
      int idx = rr * 256 + tid;
      int m   = idx >> 4;             // 0..63
      int k4  = (idx & 15) << 2;      // 0,4,...,60
      int gk  = kb + k4;
      int gm  = m0 + m;
      float4 va = {0.f, 0.f, 0.f, 0.f};
      if (gm < n && gk < NFEAT)
        va = *reinterpret_cast<const float4*>(&x[(size_t)gm * NFEAT + gk]);
      *reinterpret_cast<uint2*>(&Ah[m][k4]) =
          make_uint2(packbf(va.x, va.y), packbf(va.z, va.w));
      *reinterpret_cast<uint2*>(&Bh[m][k4]) =
          *reinterpret_cast<const uint2*>(&whg[m * 512 + gk]);
    }
    __syncthreads();
#pragma unroll
    for (int ks = 0; ks < 2; ++ks) {
      int k0 = ks * 32 + koff;
      bf16x8 a = *reinterpret_cast<const bf16x8*>(&Ah[rowA][k0]);
#pragma unroll
      for (int c = 0; c < 4; ++c) {
        bf16x8 b = *reinterpret_cast<const bf16x8*>(&Bh[c * 16 + r][k0]);
        acc[c] = __builtin_amdgcn_mfma_f32_16x16x32_bf16(a, b, acc[c], 0, 0, 0);
      }
    }
    __syncthreads();
  }

  float rowa[4] = {0.f, 0.f, 0.f, 0.f};
  float rowb[4] = {0.f, 0.f, 0.f, 0.f};
#pragma unroll
  for (int c = 0; c < 4; ++c) {
    int col = c * 16 + r;
    float bv = bias[col], alc = al[col], arc = ar[col];
#pragma unroll
    for (int rr = 0; rr < 4; ++rr) {
      int gmo = m0 + wv * 16 + (lane >> 4) * 4 + rr;
      float v = acc[c][rr] + bv;
      v = v > 0.f ? v : 0.f;
      if (gmo < n) {
        __bf16 vb16 = (__bf16)v;
        hb[(size_t)gmo * DIM + col] = *reinterpret_cast<unsigned short*>(&vb16);
      }
      rowa[rr] = fmaf(v, alc, rowa[rr]);
      rowb[rr] = fmaf(v, arc, rowb[rr]);
    }
  }
#pragma unroll
  for (int rr = 0; rr < 4; ++rr) {
    float a = rowa[rr], b = rowb[rr];
#pragma unroll
    for (int off = 8; off > 0; off >>= 1) {
      a += __shfl_xor(a, off, 64);
      b += __shfl_xor(b, off, 64);
    }
    if (r == 0) {
      int gmo = m0 + wv * 16 + (lane >> 4) * 4 + rr;
      if (gmo < n) { hl[gmo] = a; hr[gmo] = b; }
    }
  }
}

// ---------------- 8-stream edge loop (round-12) ----------------

#define EDGE_LOOP(READ_ED)                                                   \
  for (int j = 0; j < mcnt; j += 8) {                                        \
    _Pragma("unroll")                                                        \
    for (int u = 0; u < 8; ++u) {                                            \
      int idx = j + u;                                                       \
      bool valid = idx < cnt;                                                \
      int ci = valid ? s + idx : 0;                                          \
      int2 ed = READ_ED(ci);                                                 \
      int off = valid ? ed.x : 0;                                            \
      float cf = valid ? __int_as_float(ed.y) : 0.f;                         \
      uint4 hv = *reinterpret_cast<const uint4*>((const char*)hb + off + q16);\
      acc0 = fmaf(cf, bflo(hv.x), acc0); acc1 = fmaf(cf, bfhi(hv.x), acc1);  \
      acc2 = fmaf(cf, bflo(hv.y), acc2); acc3 = fmaf(cf, bfhi(hv.y), acc3);  \
      acc4 = fmaf(cf, bflo(hv.z), acc4); acc5 = fmaf(cf, bfhi(hv.z), acc5);  \
      acc6 = fmaf(cf, bflo(hv.w), acc6); acc7 = fmaf(cf, bfhi(hv.w), acc7);  \
    }                                                                        \
  }
#define RD_LDS(ci) eds[ci]
#define RD_GLB(ci) ({ int2 _e = edata[e0 + (ci)];                            \
      float _c = fast_tanh(hlv[_e.x] + hrd) * __int_as_float(_e.y);          \
      make_int2(_e.x * 128, __float_as_int(_c)); })

#define STAGE_EDGES(HLV, HRL)                                                \
  for (int i = tid; i < nE && i < LDSE; i += 256) {                          \
    int2 e = edata[e0 + i];                                                  \
    int key = e0 + i;                                                        \
    int nd = 0;                                                              \
    _Pragma("unroll")                                                        \
    for (int st = 16; st >= 1; st >>= 1)                                     \
      if (offs_l[nd + st] <= key) nd += st;                                  \
    float c = fast_tanh(HLV[e.x] + HRL[nd]) * __int_as_float(e.y);           \
    eds[i] = make_int2(e.x * 128, __float_as_int(c));                        \
  }

#define AGG_PROLOGUE()                                                       \
  const int tid  = threadIdx.x;                                              \
  const int lane = tid & 63;                                                 \
  const int wv   = tid >> 6;                                                 \
  const int g    = lane >> 3;          /* group 0..7 -> node */              \
  const int q    = lane & 7;           /* dim octet */                       \
  const int q16  = q << 4;                                                   \
  const int n0   = blockIdx.x * NPB;                                         \
  if (tid <= NPB) {                                                          \
    int nd = n0 + tid;                                                       \
    offs_l[tid] = offs[nd < n ? nd : n];                                     \
  }                                                                          \
  if (tid < NPB) {                                                           \
    int nd = n0 + tid;                                                       \
    hr_l[tid] = nd < n ? hrv[nd] : 0.f;                                      \
  }

#define AGG_BODY()                                                           \
  const int e0 = offs_l[0];                                                  \
  const int nE = offs_l[NPB] - e0;                                           \
  STAGE_EDGES(hlv, hr_l)                                                     \
  __syncthreads();                                                           \
  const int node = n0 + wv * 8 + g;                                          \
  int s = 0, cnt = 0;                                                        \
  float hrd = 0.f;                                                           \
  if (node < n) {                                                            \
    s = offs_l[wv * 8 + g] - e0;                                             \
    cnt = offs_l[wv * 8 + g + 1] - e0 - s;                                   \
    hrd = hr_l[wv * 8 + g];                                                  \
  }                                                                          \
  int mcnt = cnt;                                                            \
  mcnt = max(mcnt, __shfl_xor(mcnt, 8, 64));                                 \
  mcnt = max(mcnt, __shfl_xor(mcnt, 16, 64));                                \
  mcnt = max(mcnt, __shfl_xor(mcnt, 32, 64));                                \
  float acc0 = 0.f, acc1 = 0.f, acc2 = 0.f, acc3 = 0.f;                      \
  float acc4 = 0.f, acc5 = 0.f, acc6 = 0.f, acc7 = 0.f;                      \
  if (nE <= LDSE) { EDGE_LOOP(RD_LDS) } else { EDGE_LOOP(RD_GLB) }

// ---------------- FAConv layer-1 agg + fused layer-2 dots ----------------

__global__ __launch_bounds__(256) void agg1_kernel(const unsigned short* __restrict__ hb,
                                                   const int2* __restrict__ edata,
                                                   const int* __restrict__ offs,
                                                   const float* __restrict__ hlv,
                                                   const float* __restrict__ hrv,
                                                   const float* __restrict__ al2,
                                                   const float* __restrict__ ar2,
                                                   unsigned short* __restrict__ h1b,
                                                   float* __restrict__ hl2,
                                                   float* __restrict__ hr2, int n) {
  __shared__ int2 eds[LDSE];
  __shared__ int offs_l[NPB + 1];
  __shared__ float hr_l[NPB];
  AGG_PROLOGUE()
  __syncthreads();
  AGG_BODY()

  if (node < n) {
    uint4 rv = *reinterpret_cast<const uint4*>((const char*)hb + (size_t)node * 128 + q16);
    float v0 = fmaf(EPS_FA, bflo(rv.x), acc0);
    float v1 = fmaf(EPS_FA, bfhi(rv.x), acc1);
    float v2 = fmaf(EPS_FA, bflo(rv.y), acc2);
    float v3 = fmaf(EPS_FA, bfhi(rv.y), acc3);
    float v4 = fmaf(EPS_FA, bflo(rv.z), acc4);
    float v5 = fmaf(EPS_FA, bfhi(rv.z), acc5);
    float v6 = fmaf(EPS_FA, bflo(rv.w), acc6);
    float v7 = fmaf(EPS_FA, bfhi(rv.w), acc7);
    uint4 pk = make_uint4(packbf(v0, v1), packbf(v2, v3), packbf(v4, v5), packbf(v6, v7));
    *reinterpret_cast<uint4*>((char*)h1b + (size_t)node * 128 + q16) = pk;
    const float4 ala = *reinterpret_cast<const float4*>(al2 + q * 8);
    const float4 alb = *reinterpret_cast<const float4*>(al2 + q * 8 + 4);
    const float4 ara = *reinterpret_cast<const float4*>(ar2 + q * 8);
    const float4 arb = *reinterpret_cast<const float4*>(ar2 + q * 8 + 4);
    float a = v0 * ala.x + v1 * ala.y + v2 * ala.z + v3 * ala.w
            + v4 * alb.x + v5 * alb.y + v6 * alb.z + v7 * alb.w;
    float b = v0 * ara.x + v1 * ara.y + v2 * ara.z + v3 * ara.w
            + v4 * arb.x + v5 * arb.y + v6 * arb.z + v7 * arb.w;
#pragma unroll
    for (int off = 4; off > 0; off >>= 1) {
      a += __shfl_xor(a, off, 64);
      b += __shfl_xor(b, off, 64);
    }
    if (q == 0) { hl2[node] = a; hr2[node] = b; }
  }
}

// ---------------- layer-2 agg fused with classifier + log_softmax ----------------
// rowbuf padded to 68 floats/row: classifier broadcast reads spread across banks
// (r15 diagnostic measured 4.0M SQ_LDS_BANK_CONFLICT with stride-64 rows).

__global__ __launch_bounds__(256) void agg_cls_kernel(const unsigned short* __restrict__ hb,
                                                      const unsigned short* __restrict__ rawb,
                                                      const int2* __restrict__ edata,
                                                      const int* __restrict__ offs,
                                                      const float* __restrict__ hlv,
                                                      const float* __restrict__ hrv,
                                                      const float* __restrict__ t2w,
                                                      const float* __restrict__ t2b,
                                                      float* __restrict__ out, int n) {
  __shared__ int2 eds[LDSE];
  __shared__ int offs_l[NPB + 1];
  __shared__ float hr_l[NPB];
  __shared__ float t2s[DIM * NCLS];     // [k][cls]
  __shared__ float rowbuf[NPB][68];     // +4 pad: bank = (4*nl + k) % 32
  AGG_PROLOGUE()
  for (int i = tid; i < DIM * NCLS; i += 256) {
    int k = i / NCLS, cls = i - k * NCLS;
    t2s[i] = t2w[cls * DIM + k];
  }
  __syncthreads();
  AGG_BODY()

  if (node >= n) return;
  const int nl = wv * 8 + g;
  {
    uint4 rv = *reinterpret_cast<const uint4*>((const char*)rawb + (size_t)node * 128 + q16);
    float4 va, vb;
    va.x = fmaf(EPS_FA, bflo(rv.x), acc0);
    va.y = fmaf(EPS_FA, bfhi(rv.x), acc1);
    va.z = fmaf(EPS_FA, bflo(rv.y), acc2);
    va.w = fmaf(EPS_FA, bfhi(rv.y), acc3);
    vb.x = fmaf(EPS_FA, bflo(rv.z), acc4);
    vb.y = fmaf(EPS_FA, bfhi(rv.z), acc5);
    vb.z = fmaf(EPS_FA, bflo(rv.w), acc6);
    vb.w = fmaf(EPS_FA, bfhi(rv.w), acc7);
    *reinterpret_cast<float4*>(&rowbuf[nl][q * 8])     = va;  // wave-local
    *reinterpret_cast<float4*>(&rowbuf[nl][q * 8 + 4]) = vb;
  }
  float lg[5];
#pragma unroll
  for (int j = 0; j < 5; ++j) lg[j] = t2b[q + 8 * j];
#pragma unroll
  for (int k = 0; k < DIM; ++k) {
    float rr = rowbuf[nl][k];
#pragma unroll
    for (int j = 0; j < 5; ++j)
      lg[j] = fmaf(rr, t2s[k * NCLS + q + 8 * j], lg[j]);
  }
  float mx = lg[0];
#pragma unroll
  for (int j = 1; j < 5; ++j) mx = fmaxf(mx, lg[j]);
#pragma unroll
  for (int off = 4; off > 0; off >>= 1) mx = fmaxf(mx, __shfl_xor(mx, off, 64));
  float ssum = 0.f;
#pragma unroll
  for (int j = 0; j < 5; ++j) ssum += __expf(lg[j] - mx);
#pragma unroll
  for (int off = 4; off > 0; off >>= 1) ssum += __shfl_xor(ssum, off, 64);
  float lse = mx + __logf(ssum);
  float* op = out + (size_t)node * NCLS;
#pragma unroll
  for (int j = 0; j < 5; ++j) op[q + 8 * j] = lg[j] - lse;
}

// ---------------- launch ----------------

extern "C" void kernel_launch(void* const* d_in, const int* in_sizes, int n_in,
                              void* d_out, int out_size, void* d_ws, size_t ws_size,
                              hipStream_t stream) {
  const float* x   = (const float*)d_in[0];
  const int*   ei  = (const int*)d_in[1];
  const float* ewt = (const float*)d_in[2];
  const float* t1w = (const float*)d_in[3];
  const float* t1b = (const float*)d_in[4];
  const float* al1 = (const float*)d_in[5];
  const float* ar1 = (const float*)d_in[6];
  const float* al2 = (const float*)d_in[7];
  const float* ar2 = (const float*)d_in[8];
  const float* t2w = (const float*)d_in[9];
  const float* t2b = (const float*)d_in[10];
  float* out = (float*)d_out;

  const int n = in_sizes[0] / NFEAT;   // 100000
  const int E = in_sizes[2];           // 1600000
  const int* srcp = ei;
  const int* dstp = ei + E;

  char* p = (char*)d_ws;
  auto alloc = [&](size_t bytes) {
    char* q = p;
    p += (bytes + 255) & ~(size_t)255;
    return q;
  };
  unsigned short* h0b = (unsigned short*)alloc((size_t)n * DIM * 2);
  unsigned short* h1b = (unsigned short*)alloc((size_t)n * DIM * 2);
  float* hl    = (float*)alloc((size_t)n * 4);
  float* hr    = (float*)alloc((size_t)n * 4);
  float* hl2   = (float*)alloc((size_t)n * 4);
  float* hr2   = (float*)alloc((size_t)n * 4);
  int*   offs  = (int*)alloc((size_t)(n + 1) * 4);
  int2*  edata = (int2*)alloc((size_t)E * 8);
  int2*  tmp   = (int2*)alloc((size_t)E * 8);
  unsigned short* whg = (unsigned short*)alloc((size_t)DIM * 512 * 2);
  int*   counts = (int*)alloc((size_t)256 * NCHUNK * 4);
  int*   buktot = (int*)alloc(256 * 4);
  int*   bukbase= (int*)alloc(257 * 4);

  const int nbuk = (n + 511) >> BSH;                 // 196
  const int epc  = (E + NCHUNK - 1) / NCHUNK;        // 6250

  hist2d_kernel<<<NCHUNK, 256, 0, stream>>>(dstp, counts, E, epc, nbuk);
  scan_chunks_kernel<<<nbuk, 256, 0, stream>>>(counts, buktot);
  scan_buckets_kernel<<<1, 64, 0, stream>>>(buktot, bukbase, nbuk);
  scatter_bucket_kernel<<<NCHUNK, 256, 0, stream>>>(srcp, dstp, ewt, counts, bukbase,
                                                    tmp, E, epc, nbuk);
  place_kernel<<<nbuk, 256, 0, stream>>>(tmp, bukbase, edata, offs, n, nbuk);

  prep_w_kernel<<<(DIM * 512) / 256, 256, 0, stream>>>(t1w, whg);
  gemm1_kernel<<<(n + 63) / 64, 256, 0, stream>>>(x, whg, t1b, al1, ar1,
                                                  h0b, hl, hr, n);

  const int ab = (n + NPB - 1) / NPB;
  agg1_kernel<<<ab, 256, 0, stream>>>(h0b, edata, offs, hl, hr, al2, ar2, h1b, hl2, hr2, n);
  agg_cls_kernel<<<ab, 256, 0, stream>>>(h1b, h0b, edata, offs, hl2, hr2, t2w, t2b, out, n);
}